// Round 5
// baseline (533.517 us; speedup 1.0000x reference)
//
#include <hip/hip_runtime.h>
#include <hip/hip_bf16.h>

#define B_ 4
#define S_ 4096
#define D_ 1024
#define NT_ 32        // S_/128
#define PAIRS_ 528    // NT_*(NT_+1)/2 lower-triangle tile pairs

typedef __attribute__((ext_vector_type(8))) short short8;
typedef __attribute__((ext_vector_type(4))) float f32x4;

__device__ __forceinline__ unsigned short f2bf(float f) {
    union { float f; unsigned u; } v; v.f = f;
    unsigned u = v.u;
    return (unsigned short)((u + 0x7fffu + ((u >> 16) & 1u)) >> 16);
}

// async global->LDS, 16B per lane. LDS dst is wave-uniform base + lane*16.
__device__ __forceinline__ void gld_lds16(const unsigned short* g, unsigned short* l) {
    __builtin_amdgcn_global_load_lds((const __attribute__((address_space(1))) void*)g,
                                     (__attribute__((address_space(3))) void*)l, 16, 0, 0);
}

// stage a 128x32 bf16 tile (global row stride = ld elems) into contiguous LDS [128][32]
__device__ __forceinline__ void stage128x32(const unsigned short* gbase, size_t ld,
                                            unsigned short* ls, int tid) {
    const int r = tid >> 2;
    const int c = (tid & 3) * 8;
    unsigned short* lw = ls + tid * 8;
    gld_lds16(gbase + (size_t)r * ld + c, lw);
    gld_lds16(gbase + (size_t)(r + 64) * ld + c, lw + 2048);
}

// ---------------------------------------------------------------------------
// prep_x: fp32 x -> bf16 xb
// ---------------------------------------------------------------------------
__global__ __launch_bounds__(256) void prep_x(const float* __restrict__ x,
                                              unsigned short* __restrict__ xb) {
    size_t i = ((size_t)blockIdx.x * 256 + threadIdx.x) * 8;
    float4 a = *(const float4*)&x[i];
    float4 b = *(const float4*)&x[i + 4];
    unsigned u0 = (unsigned)f2bf(a.x) | ((unsigned)f2bf(a.y) << 16);
    unsigned u1 = (unsigned)f2bf(a.z) | ((unsigned)f2bf(a.w) << 16);
    unsigned u2 = (unsigned)f2bf(b.x) | ((unsigned)f2bf(b.y) << 16);
    unsigned u3 = (unsigned)f2bf(b.z) | ((unsigned)f2bf(b.w) << 16);
    uint4 val; val.x = u0; val.y = u1; val.z = u2; val.w = u3;
    *(uint4*)&xb[i] = val;
}

// ---------------------------------------------------------------------------
// prep_w: W[k][n] fp32 -> Wt[n][k] bf16
// ---------------------------------------------------------------------------
__global__ __launch_bounds__(256) void prep_w(const float* __restrict__ Wq,
                                              const float* __restrict__ Wk,
                                              const float* __restrict__ Wv,
                                              unsigned short* __restrict__ Wt) {
    __shared__ float ls[64 * 65];
    const int z = blockIdx.z;
    const float* __restrict__ W = (z == 0) ? Wq : (z == 1) ? Wk : Wv;
    unsigned short* __restrict__ Wtz = Wt + (size_t)z * D_ * D_;
    const int k0 = blockIdx.y * 64, n0 = blockIdx.x * 64;
    const int tid = threadIdx.x;
    #pragma unroll
    for (int i = 0; i < 16; ++i) {
        int lin = i * 256 + tid, r = lin >> 6, c = lin & 63;
        ls[r * 65 + c] = W[(size_t)(k0 + r) * D_ + n0 + c];
    }
    __syncthreads();
    #pragma unroll
    for (int i = 0; i < 16; ++i) {
        int lin = i * 256 + tid, r = lin >> 6, c = lin & 63;
        Wtz[(size_t)(n0 + r) * D_ + k0 + c] = f2bf(ls[c * 65 + r]);
    }
}

// ---------------------------------------------------------------------------
// qkv_gemm: Y = xb @ Wt_z^T. XCD-swizzled: XCD r owns m-tiles r*16..r*16+15,
// n innermost -> A-tile (256KB) and all B (2MB) stay L2-resident per XCD.
// ---------------------------------------------------------------------------
__global__ __launch_bounds__(256) void qkv_gemm(
    const unsigned short* __restrict__ xb, const unsigned short* __restrict__ Wt,
    unsigned short* __restrict__ Q, unsigned short* __restrict__ K,
    unsigned short* __restrict__ V)
{
    __shared__ __align__(16) unsigned short lsA[4096];
    __shared__ __align__(16) unsigned short lsB[4096];

    const int z = blockIdx.z;
    unsigned short* __restrict__ Y = (z == 0) ? Q : (z == 1) ? K : V;
    const float scale = (z == 0) ? 0.03125f : 1.0f;

    const int lin = blockIdx.x + 8 * blockIdx.y;   // 0..1023, xcd = lin & 7
    const int xcd = lin & 7;
    const int s = lin >> 3;                        // 0..127
    const int m0 = (xcd * 16 + (s >> 3)) * 128;
    const int n0 = (s & 7) * 128;

    const int tid = threadIdx.x, lane = tid & 63, w = tid >> 6;
    const int wm = w >> 1, wn = w & 1, quad = lane >> 4, ln = lane & 15;

    const unsigned short* Ab = xb + (size_t)m0 * D_;
    const unsigned short* Bb = Wt + (size_t)z * D_ * D_ + (size_t)n0 * D_;

    f32x4 acc[4][4] = {};

    for (int et = 0; et < D_ / 32; ++et) {
        stage128x32(Ab + et * 32, D_, lsA, tid);
        stage128x32(Bb + et * 32, D_, lsB, tid);
        __syncthreads();
        short8 af[4], bfr[4];
        #pragma unroll
        for (int mf = 0; mf < 4; ++mf)
            af[mf] = *(const short8*)&lsA[(wm * 64 + mf * 16 + ln) * 32 + quad * 8];
        #pragma unroll
        for (int nf = 0; nf < 4; ++nf)
            bfr[nf] = *(const short8*)&lsB[(wn * 64 + nf * 16 + ln) * 32 + quad * 8];
        #pragma unroll
        for (int mf = 0; mf < 4; ++mf)
            #pragma unroll
            for (int nf = 0; nf < 4; ++nf)
                acc[mf][nf] = __builtin_amdgcn_mfma_f32_16x16x32_bf16(af[mf], bfr[nf], acc[mf][nf], 0, 0, 0);
        __syncthreads();
    }

    #pragma unroll
    for (int mf = 0; mf < 4; ++mf)
        #pragma unroll
        for (int nf = 0; nf < 4; ++nf)
            #pragma unroll
            for (int r = 0; r < 4; ++r) {
                int row = m0 + wm * 64 + mf * 16 + quad * 4 + r;
                int col = n0 + wn * 64 + nf * 16 + ln;
                Y[(size_t)row * D_ + col] = f2bf(acc[mf][nf][r] * scale);
            }
}

// ---------------------------------------------------------------------------
// vt_trans: V[b][s][e] -> Vt[b][e][s]
// ---------------------------------------------------------------------------
__global__ __launch_bounds__(256) void vt_trans(const unsigned short* __restrict__ V,
                                                unsigned short* __restrict__ Vt) {
    __shared__ unsigned short ls[64 * 66];
    const int s0 = blockIdx.x * 64, e0 = blockIdx.y * 64, b = blockIdx.z;
    const int tid = threadIdx.x;
    const size_t base = (size_t)b * S_ * D_;
    #pragma unroll
    for (int i = 0; i < 16; ++i) {
        int lin = i * 256 + tid, r = lin >> 6, c = lin & 63;
        ls[r * 66 + c] = V[base + (size_t)(s0 + r) * D_ + e0 + c];
    }
    __syncthreads();
    const size_t baseT = (size_t)b * D_ * S_;
    #pragma unroll
    for (int i = 0; i < 16; ++i) {
        int lin = i * 256 + tid, r = lin >> 6, c = lin & 63;
        Vt[baseT + (size_t)(e0 + r) * S_ + s0 + c] = ls[c * 66 + r];
    }
}

// ---------------------------------------------------------------------------
// qk_pexp: per lower-tri tile pair: P = exp(Q@K^T) bf16 tile-packed, partial l.
// XCD-swizzled: XCD r owns qt rows {r, 31-r, 8+r, 23-r} (66 blocks each,
// balanced); kt streams within a row -> Q-tile L2-local.
// ---------------------------------------------------------------------------
__global__ __launch_bounds__(256) void qk_pexp(
    const unsigned short* __restrict__ Q, const unsigned short* __restrict__ K,
    unsigned short* __restrict__ P, float* __restrict__ lpart)
{
    __shared__ __align__(16) unsigned short lsA[4096];
    __shared__ __align__(16) unsigned short lsB[4096];
    __shared__ float sml[2][128];

    const int l = blockIdx.x, b = blockIdx.y;
    const int r = l & 7;          // xcd
    const int s = l >> 3;         // 0..65
    int qt, kt;
    if (s < r + 1)            { qt = r;      kt = s; }
    else if (s < 33)          { qt = 31 - r; kt = s - (r + 1); }
    else if (s < 42 + r)      { qt = 8 + r;  kt = s - 33; }
    else                      { qt = 23 - r; kt = s - (42 + r); }
    const int p = qt * (qt + 1) / 2 + kt;

    const int q0 = qt * 128, k0 = kt * 128;
    const int tid = threadIdx.x, lane = tid & 63, w = tid >> 6;
    const int wm = w >> 1, wn = w & 1, quad = lane >> 4, ln = lane & 15;
    const size_t base = (size_t)b * S_ * D_;

    const unsigned short* Qb = Q + base + (size_t)q0 * D_;
    const unsigned short* Kb = K + base + (size_t)k0 * D_;

    f32x4 acc[4][4] = {};
    for (int et = 0; et < D_ / 32; ++et) {
        stage128x32(Qb + et * 32, D_, lsA, tid);
        stage128x32(Kb + et * 32, D_, lsB, tid);
        __syncthreads();
        short8 af[4], bfr[4];
        #pragma unroll
        for (int mf = 0; mf < 4; ++mf)
            af[mf] = *(const short8*)&lsA[(wm * 64 + mf * 16 + ln) * 32 + quad * 8];
        #pragma unroll
        for (int nf = 0; nf < 4; ++nf)
            bfr[nf] = *(const short8*)&lsB[(wn * 64 + nf * 16 + ln) * 32 + quad * 8];
        #pragma unroll
        for (int mf = 0; mf < 4; ++mf)
            #pragma unroll
            for (int nf = 0; nf < 4; ++nf)
                acc[mf][nf] = __builtin_amdgcn_mfma_f32_16x16x32_bf16(af[mf], bfr[nf], acc[mf][nf], 0, 0, 0);
        __syncthreads();
    }

    const bool diag = (kt == qt);
    unsigned short* Pt = P + ((size_t)b * PAIRS_ + p) * (128 * 128);

    #pragma unroll
    for (int mf = 0; mf < 4; ++mf)
        #pragma unroll
        for (int rr = 0; rr < 4; ++rr) {
            int rowq = wm * 64 + mf * 16 + quad * 4 + rr;
            float lsum = 0.0f;
            #pragma unroll
            for (int nf = 0; nf < 4; ++nf) {
                int ckey = wn * 64 + nf * 16 + ln;
                float sc = acc[mf][nf][rr];
                float pe = (diag && ckey > rowq) ? 0.0f : __expf(fminf(sc, 60.0f));
                Pt[rowq * 128 + ckey] = f2bf(pe);
                lsum += pe;
            }
            #pragma unroll
            for (int off = 1; off < 16; off <<= 1)
                lsum += __shfl_xor(lsum, off);
            if (ln == 0) sml[wn][rowq] = lsum;
        }
    __syncthreads();

    if (tid < 128)
        lpart[((size_t)b * PAIRS_ + p) * 128 + tid] = sml[0][tid] + sml[1][tid];
}

// ---------------------------------------------------------------------------
// merge_il: il[b][q] = 1 / sum_kt l_t
// ---------------------------------------------------------------------------
__global__ __launch_bounds__(128) void merge_il(const float* __restrict__ lpart,
                                                float* __restrict__ il) {
    const int qt = blockIdx.x, b = blockIdx.y;
    const int row = threadIdx.x;
    const int pbase = qt * (qt + 1) / 2;
    float l = 0.0f;
    for (int kt = 0; kt <= qt; ++kt)
        l += lpart[((size_t)b * PAIRS_ + pbase + kt) * 128 + row];
    il[(size_t)b * S_ + qt * 128 + row] = 1.0f / l;
}

// ---------------------------------------------------------------------------
// pv_gemm: O = (P @ V) * il. 128q x 256d tiles (halves P re-staging, 32 MFMA
// per substep per wave). XCD map: XCD r -> dt = r&3, balanced qt halves,
// heavy-qt first. Vt d-slice (2MB) is XCD-local.
// ---------------------------------------------------------------------------
__global__ __launch_bounds__(256) void pv_gemm(
    const unsigned short* __restrict__ P, const unsigned short* __restrict__ Vt,
    const float* __restrict__ il, float* __restrict__ O)
{
    __shared__ __align__(16) unsigned short lsA[4096];
    __shared__ __align__(16) unsigned short lsB[8192];

    const int l = blockIdx.x;            // 0..511
    const int b = l >> 7;
    const int l7 = l & 127;
    const int r = l7 & 7;                // xcd
    const int s = l7 >> 3;               // 0..15
    const int g = r >> 2;
    const int dt = r & 3;
    const int qt = (g == 0) ? ((s < 8) ? 31 - s : 15 - s) : (23 - s);

    const int q0 = qt * 128, d0 = dt * 256;
    const int tid = threadIdx.x, lane = tid & 63, w = tid >> 6;
    const int wm = w >> 1, wn = w & 1, quad = lane >> 4, ln = lane & 15;
    const int pbase = qt * (qt + 1) / 2;

    const unsigned short* Vtb = Vt + ((size_t)b * D_ + d0) * S_;

    f32x4 acc[4][8] = {};

    for (int ktile = 0; ktile <= qt; ++ktile) {
        const unsigned short* Ptile = P + ((size_t)b * PAIRS_ + pbase + ktile) * (128 * 128);
        #pragma unroll 1
        for (int sub = 0; sub < 4; ++sub) {
            stage128x32(Ptile + sub * 32, 128, lsA, tid);
            stage128x32(Vtb + ktile * 128 + sub * 32, S_, lsB, tid);
            stage128x32(Vtb + 128 * S_ + ktile * 128 + sub * 32, S_, lsB + 4096, tid);
            __syncthreads();
            short8 af[4], bfr[8];
            #pragma unroll
            for (int mf = 0; mf < 4; ++mf)
                af[mf] = *(const short8*)&lsA[(wm * 64 + mf * 16 + ln) * 32 + quad * 8];
            #pragma unroll
            for (int nf = 0; nf < 8; ++nf)
                bfr[nf] = *(const short8*)&lsB[(wn * 128 + nf * 16 + ln) * 32 + quad * 8];
            #pragma unroll
            for (int mf = 0; mf < 4; ++mf)
                #pragma unroll
                for (int nf = 0; nf < 8; ++nf)
                    acc[mf][nf] = __builtin_amdgcn_mfma_f32_16x16x32_bf16(af[mf], bfr[nf], acc[mf][nf], 0, 0, 0);
            __syncthreads();
        }
    }

    #pragma unroll
    for (int mf = 0; mf < 4; ++mf) {
        float ilv[4];
        #pragma unroll
        for (int rr = 0; rr < 4; ++rr)
            ilv[rr] = il[(size_t)b * S_ + q0 + wm * 64 + mf * 16 + quad * 4 + rr];
        #pragma unroll
        for (int nf = 0; nf < 8; ++nf)
            #pragma unroll
            for (int rr = 0; rr < 4; ++rr) {
                int rowq = q0 + wm * 64 + mf * 16 + quad * 4 + rr;
                int col = d0 + wn * 128 + nf * 16 + ln;
                O[((size_t)b * S_ + rowq) * D_ + col] = acc[mf][nf][rr] * ilv[rr];
            }
    }
}

extern "C" void kernel_launch(void* const* d_in, const int* in_sizes, int n_in,
                              void* d_out, int out_size, void* d_ws, size_t ws_size,
                              hipStream_t stream) {
    const float* x  = (const float*)d_in[0];
    const float* Wq = (const float*)d_in[1];
    const float* Wk = (const float*)d_in[2];
    const float* Wv = (const float*)d_in[3];

    const size_t nQ = (size_t)B_ * S_ * D_;
    const size_t nP = (size_t)B_ * PAIRS_ * 128 * 128;

    unsigned short* P  = (unsigned short*)d_ws;
    unsigned short* V  = P;                       // alias: dead before P written
    unsigned short* Q  = P + nP;
    unsigned short* K  = Q + nQ;
    unsigned short* Vt = K + nQ;
    unsigned short* xb = Vt;                      // alias: dead before Vt written
    unsigned short* Wt = Vt + nQ;
    float* lpart = (float*)(Wt + (size_t)3 * D_ * D_);
    float* il    = lpart + (size_t)B_ * PAIRS_ * 128;
    float* O = (float*)d_out;

    hipLaunchKernelGGL(prep_x, dim3(8192), dim3(256), 0, stream, x, xb);
    hipLaunchKernelGGL(prep_w, dim3(16, 16, 3), dim3(256), 0, stream, Wq, Wk, Wv, Wt);
    hipLaunchKernelGGL(qkv_gemm, dim3(8, 128, 3), dim3(256), 0, stream, xb, Wt, Q, K, V);
    hipLaunchKernelGGL(vt_trans, dim3(64, 16, B_), dim3(256), 0, stream, V, Vt);
    hipLaunchKernelGGL(qk_pexp, dim3(PAIRS_, B_), dim3(256), 0, stream, Q, K, P, lpart);
    hipLaunchKernelGGL(merge_il, dim3(NT_, B_), dim3(128), 0, stream, lpart, il);
    hipLaunchKernelGGL(pv_gemm, dim3(512), dim3(256), 0, stream, P, Vt, il, O);
}

// Round 6
// 465.852 us; speedup vs baseline: 1.1452x; 1.1452x over previous
//
#include <hip/hip_runtime.h>
#include <hip/hip_bf16.h>

#define B_ 4
#define S_ 4096
#define D_ 1024
#define NT_ 32        // S_/128
#define PAIRS_ 528    // NT_*(NT_+1)/2 lower-triangle tile pairs

typedef __attribute__((ext_vector_type(8))) short short8;
typedef __attribute__((ext_vector_type(4))) float f32x4;

__device__ __forceinline__ unsigned short f2bf(float f) {
    union { float f; unsigned u; } v; v.f = f;
    unsigned u = v.u;
    return (unsigned short)((u + 0x7fffu + ((u >> 16) & 1u)) >> 16);
}

// async global->LDS, 16B per lane. LDS dst is wave-uniform base + lane*16.
__device__ __forceinline__ void gld_lds16(const unsigned short* g, unsigned short* l) {
    __builtin_amdgcn_global_load_lds((const __attribute__((address_space(1))) void*)g,
                                     (__attribute__((address_space(3))) void*)l, 16, 0, 0);
}

// stage a 128x32 bf16 tile (global row stride = ld elems) into contiguous LDS [128][32]
__device__ __forceinline__ void stage128x32(const unsigned short* gbase, size_t ld,
                                            unsigned short* ls, int tid) {
    const int r = tid >> 2;
    const int c = (tid & 3) * 8;
    unsigned short* lw = ls + tid * 8;
    gld_lds16(gbase + (size_t)r * ld + c, lw);
    gld_lds16(gbase + (size_t)(r + 64) * ld + c, lw + 2048);
}

// ---------------------------------------------------------------------------
// prep_x: fp32 x -> bf16 xb
// ---------------------------------------------------------------------------
__global__ __launch_bounds__(256) void prep_x(const float* __restrict__ x,
                                              unsigned short* __restrict__ xb) {
    size_t i = ((size_t)blockIdx.x * 256 + threadIdx.x) * 8;
    float4 a = *(const float4*)&x[i];
    float4 b = *(const float4*)&x[i + 4];
    unsigned u0 = (unsigned)f2bf(a.x) | ((unsigned)f2bf(a.y) << 16);
    unsigned u1 = (unsigned)f2bf(a.z) | ((unsigned)f2bf(a.w) << 16);
    unsigned u2 = (unsigned)f2bf(b.x) | ((unsigned)f2bf(b.y) << 16);
    unsigned u3 = (unsigned)f2bf(b.z) | ((unsigned)f2bf(b.w) << 16);
    uint4 val; val.x = u0; val.y = u1; val.z = u2; val.w = u3;
    *(uint4*)&xb[i] = val;
}

// ---------------------------------------------------------------------------
// prep_w: W[k][n] fp32 -> Wt[n][k] bf16
// ---------------------------------------------------------------------------
__global__ __launch_bounds__(256) void prep_w(const float* __restrict__ Wq,
                                              const float* __restrict__ Wk,
                                              const float* __restrict__ Wv,
                                              unsigned short* __restrict__ Wt) {
    __shared__ float ls[64 * 65];
    const int z = blockIdx.z;
    const float* __restrict__ W = (z == 0) ? Wq : (z == 1) ? Wk : Wv;
    unsigned short* __restrict__ Wtz = Wt + (size_t)z * D_ * D_;
    const int k0 = blockIdx.y * 64, n0 = blockIdx.x * 64;
    const int tid = threadIdx.x;
    #pragma unroll
    for (int i = 0; i < 16; ++i) {
        int lin = i * 256 + tid, r = lin >> 6, c = lin & 63;
        ls[r * 65 + c] = W[(size_t)(k0 + r) * D_ + n0 + c];
    }
    __syncthreads();
    #pragma unroll
    for (int i = 0; i < 16; ++i) {
        int lin = i * 256 + tid, r = lin >> 6, c = lin & 63;
        Wtz[(size_t)(n0 + r) * D_ + k0 + c] = f2bf(ls[c * 65 + r]);
    }
}

// ---------------------------------------------------------------------------
// qkv_gemm: Y = xb @ Wt_z^T. XCD-swizzled: XCD r owns m-tiles r*16..r*16+15,
// n innermost.
// ---------------------------------------------------------------------------
__global__ __launch_bounds__(256) void qkv_gemm(
    const unsigned short* __restrict__ xb, const unsigned short* __restrict__ Wt,
    unsigned short* __restrict__ Q, unsigned short* __restrict__ K,
    unsigned short* __restrict__ V)
{
    __shared__ __align__(16) unsigned short lsA[4096];
    __shared__ __align__(16) unsigned short lsB[4096];

    const int z = blockIdx.z;
    unsigned short* __restrict__ Y = (z == 0) ? Q : (z == 1) ? K : V;
    const float scale = (z == 0) ? 0.03125f : 1.0f;

    const int lin = blockIdx.x + 8 * blockIdx.y;   // 0..1023, xcd = lin & 7
    const int xcd = lin & 7;
    const int s = lin >> 3;                        // 0..127
    const int m0 = (xcd * 16 + (s >> 3)) * 128;
    const int n0 = (s & 7) * 128;

    const int tid = threadIdx.x, lane = tid & 63, w = tid >> 6;
    const int wm = w >> 1, wn = w & 1, quad = lane >> 4, ln = lane & 15;

    const unsigned short* Ab = xb + (size_t)m0 * D_;
    const unsigned short* Bb = Wt + (size_t)z * D_ * D_ + (size_t)n0 * D_;

    f32x4 acc[4][4] = {};

    for (int et = 0; et < D_ / 32; ++et) {
        stage128x32(Ab + et * 32, D_, lsA, tid);
        stage128x32(Bb + et * 32, D_, lsB, tid);
        __syncthreads();
        short8 af[4], bfr[4];
        #pragma unroll
        for (int mf = 0; mf < 4; ++mf)
            af[mf] = *(const short8*)&lsA[(wm * 64 + mf * 16 + ln) * 32 + quad * 8];
        #pragma unroll
        for (int nf = 0; nf < 4; ++nf)
            bfr[nf] = *(const short8*)&lsB[(wn * 64 + nf * 16 + ln) * 32 + quad * 8];
        #pragma unroll
        for (int mf = 0; mf < 4; ++mf)
            #pragma unroll
            for (int nf = 0; nf < 4; ++nf)
                acc[mf][nf] = __builtin_amdgcn_mfma_f32_16x16x32_bf16(af[mf], bfr[nf], acc[mf][nf], 0, 0, 0);
        __syncthreads();
    }

    #pragma unroll
    for (int mf = 0; mf < 4; ++mf)
        #pragma unroll
        for (int nf = 0; nf < 4; ++nf)
            #pragma unroll
            for (int r = 0; r < 4; ++r) {
                int row = m0 + wm * 64 + mf * 16 + quad * 4 + r;
                int col = n0 + wn * 64 + nf * 16 + ln;
                Y[(size_t)row * D_ + col] = f2bf(acc[mf][nf][r] * scale);
            }
}

// ---------------------------------------------------------------------------
// vt_trans: V[b][s][e] -> Vt[b][e][s]
// ---------------------------------------------------------------------------
__global__ __launch_bounds__(256) void vt_trans(const unsigned short* __restrict__ V,
                                                unsigned short* __restrict__ Vt) {
    __shared__ unsigned short ls[64 * 66];
    const int s0 = blockIdx.x * 64, e0 = blockIdx.y * 64, b = blockIdx.z;
    const int tid = threadIdx.x;
    const size_t base = (size_t)b * S_ * D_;
    #pragma unroll
    for (int i = 0; i < 16; ++i) {
        int lin = i * 256 + tid, r = lin >> 6, c = lin & 63;
        ls[r * 66 + c] = V[base + (size_t)(s0 + r) * D_ + e0 + c];
    }
    __syncthreads();
    const size_t baseT = (size_t)b * D_ * S_;
    #pragma unroll
    for (int i = 0; i < 16; ++i) {
        int lin = i * 256 + tid, r = lin >> 6, c = lin & 63;
        Vt[baseT + (size_t)(e0 + r) * S_ + s0 + c] = ls[c * 66 + r];
    }
}

// ---------------------------------------------------------------------------
// qk_pexp: per lower-tri tile pair: P = exp(Q@K^T) bf16 tile-packed, partial l.
// XCD-swizzled: XCD r owns qt rows {r, 31-r, 8+r, 23-r} (66 blocks each).
// ---------------------------------------------------------------------------
__global__ __launch_bounds__(256) void qk_pexp(
    const unsigned short* __restrict__ Q, const unsigned short* __restrict__ K,
    unsigned short* __restrict__ P, float* __restrict__ lpart)
{
    __shared__ __align__(16) unsigned short lsA[4096];
    __shared__ __align__(16) unsigned short lsB[4096];
    __shared__ float sml[2][128];

    const int l = blockIdx.x, b = blockIdx.y;
    const int r = l & 7;          // xcd
    const int s = l >> 3;         // 0..65
    int qt, kt;
    if (s < r + 1)            { qt = r;      kt = s; }
    else if (s < 33)          { qt = 31 - r; kt = s - (r + 1); }
    else if (s < 42 + r)      { qt = 8 + r;  kt = s - 33; }
    else                      { qt = 23 - r; kt = s - (42 + r); }
    const int p = qt * (qt + 1) / 2 + kt;

    const int q0 = qt * 128, k0 = kt * 128;
    const int tid = threadIdx.x, lane = tid & 63, w = tid >> 6;
    const int wm = w >> 1, wn = w & 1, quad = lane >> 4, ln = lane & 15;
    const size_t base = (size_t)b * S_ * D_;

    const unsigned short* Qb = Q + base + (size_t)q0 * D_;
    const unsigned short* Kb = K + base + (size_t)k0 * D_;

    f32x4 acc[4][4] = {};
    for (int et = 0; et < D_ / 32; ++et) {
        stage128x32(Qb + et * 32, D_, lsA, tid);
        stage128x32(Kb + et * 32, D_, lsB, tid);
        __syncthreads();
        short8 af[4], bfr[4];
        #pragma unroll
        for (int mf = 0; mf < 4; ++mf)
            af[mf] = *(const short8*)&lsA[(wm * 64 + mf * 16 + ln) * 32 + quad * 8];
        #pragma unroll
        for (int nf = 0; nf < 4; ++nf)
            bfr[nf] = *(const short8*)&lsB[(wn * 64 + nf * 16 + ln) * 32 + quad * 8];
        #pragma unroll
        for (int mf = 0; mf < 4; ++mf)
            #pragma unroll
            for (int nf = 0; nf < 4; ++nf)
                acc[mf][nf] = __builtin_amdgcn_mfma_f32_16x16x32_bf16(af[mf], bfr[nf], acc[mf][nf], 0, 0, 0);
        __syncthreads();
    }

    const bool diag = (kt == qt);
    unsigned short* Pt = P + ((size_t)b * PAIRS_ + p) * (128 * 128);

    #pragma unroll
    for (int mf = 0; mf < 4; ++mf)
        #pragma unroll
        for (int rr = 0; rr < 4; ++rr) {
            int rowq = wm * 64 + mf * 16 + quad * 4 + rr;
            float lsum = 0.0f;
            #pragma unroll
            for (int nf = 0; nf < 4; ++nf) {
                int ckey = wn * 64 + nf * 16 + ln;
                float sc = acc[mf][nf][rr];
                float pe = (diag && ckey > rowq) ? 0.0f : __expf(fminf(sc, 60.0f));
                Pt[rowq * 128 + ckey] = f2bf(pe);
                lsum += pe;
            }
            #pragma unroll
            for (int off = 1; off < 16; off <<= 1)
                lsum += __shfl_xor(lsum, off);
            if (ln == 0) sml[wn][rowq] = lsum;
        }
    __syncthreads();

    if (tid < 128)
        lpart[((size_t)b * PAIRS_ + p) * 128 + tid] = sml[0][tid] + sml[1][tid];
}

// ---------------------------------------------------------------------------
// merge_il: il[b][q] = 1 / sum_kt l_t
// ---------------------------------------------------------------------------
__global__ __launch_bounds__(128) void merge_il(const float* __restrict__ lpart,
                                                float* __restrict__ il) {
    const int qt = blockIdx.x, b = blockIdx.y;
    const int row = threadIdx.x;
    const int pbase = qt * (qt + 1) / 2;
    float l = 0.0f;
    for (int kt = 0; kt <= qt; ++kt)
        l += lpart[((size_t)b * PAIRS_ + pbase + kt) * 128 + row];
    il[(size_t)b * S_ + qt * 128 + row] = 1.0f / l;
}

// ---------------------------------------------------------------------------
// pv_gemm: O = (P @ V) * il. 128x128 tiles, PAIRED q-tiles for exact balance:
// each block does qt = 31-pair (heavy) then qt = pair; combined K-extent is
// always 33 ktiles -> every one of the 512 blocks does identical work
// (2 blocks/CU, 66 units/CU, zero tail). dt = lin&7 keeps Vt slice XCD-local.
// ---------------------------------------------------------------------------
__global__ __launch_bounds__(256) void pv_gemm(
    const unsigned short* __restrict__ P, const unsigned short* __restrict__ Vt,
    const float* __restrict__ il, float* __restrict__ O)
{
    __shared__ __align__(16) unsigned short lsA[4096];
    __shared__ __align__(16) unsigned short lsB[4096];

    const int l = blockIdx.x;            // 0..511
    const int dt = l & 7;                // xcd-local d-slice
    const int s = l >> 3;                // 0..63
    const int pair = s & 15;
    const int b = s >> 4;
    const int d0 = dt * 128;
    const int tid = threadIdx.x, lane = tid & 63, w = tid >> 6;
    const int wm = w >> 1, wn = w & 1, quad = lane >> 4, ln = lane & 15;

    const unsigned short* Vtb = Vt + ((size_t)b * D_ + d0) * S_;

    #pragma unroll 1
    for (int half = 0; half < 2; ++half) {
        const int qt = half ? pair : (31 - pair);   // heavy first
        const int q0 = qt * 128;
        const int pbase = qt * (qt + 1) / 2;

        f32x4 acc[4][4] = {};

        #pragma unroll 1
        for (int ktile = 0; ktile <= qt; ++ktile) {
            const unsigned short* Ptile = P + ((size_t)b * PAIRS_ + pbase + ktile) * (128 * 128);
            #pragma unroll 1
            for (int sub = 0; sub < 4; ++sub) {
                stage128x32(Ptile + sub * 32, 128, lsA, tid);
                stage128x32(Vtb + ktile * 128 + sub * 32, S_, lsB, tid);
                __syncthreads();
                short8 af[4], bfr[4];
                #pragma unroll
                for (int mf = 0; mf < 4; ++mf)
                    af[mf] = *(const short8*)&lsA[(wm * 64 + mf * 16 + ln) * 32 + quad * 8];
                #pragma unroll
                for (int nf = 0; nf < 4; ++nf)
                    bfr[nf] = *(const short8*)&lsB[(wn * 64 + nf * 16 + ln) * 32 + quad * 8];
                #pragma unroll
                for (int mf = 0; mf < 4; ++mf)
                    #pragma unroll
                    for (int nf = 0; nf < 4; ++nf)
                        acc[mf][nf] = __builtin_amdgcn_mfma_f32_16x16x32_bf16(af[mf], bfr[nf], acc[mf][nf], 0, 0, 0);
                __syncthreads();
            }
        }

        #pragma unroll
        for (int mf = 0; mf < 4; ++mf) {
            float ilv[4];
            #pragma unroll
            for (int rr = 0; rr < 4; ++rr)
                ilv[rr] = il[(size_t)b * S_ + q0 + wm * 64 + mf * 16 + quad * 4 + rr];
            #pragma unroll
            for (int nf = 0; nf < 4; ++nf)
                #pragma unroll
                for (int rr = 0; rr < 4; ++rr) {
                    int rowq = q0 + wm * 64 + mf * 16 + quad * 4 + rr;
                    int col = d0 + wn * 64 + nf * 16 + ln;
                    O[((size_t)b * S_ + rowq) * D_ + col] = acc[mf][nf][rr] * ilv[rr];
                }
        }
    }
}

extern "C" void kernel_launch(void* const* d_in, const int* in_sizes, int n_in,
                              void* d_out, int out_size, void* d_ws, size_t ws_size,
                              hipStream_t stream) {
    const float* x  = (const float*)d_in[0];
    const float* Wq = (const float*)d_in[1];
    const float* Wk = (const float*)d_in[2];
    const float* Wv = (const float*)d_in[3];

    const size_t nQ = (size_t)B_ * S_ * D_;
    const size_t nP = (size_t)B_ * PAIRS_ * 128 * 128;

    unsigned short* P  = (unsigned short*)d_ws;
    unsigned short* V  = P;                       // alias: dead before P written
    unsigned short* Q  = P + nP;
    unsigned short* K  = Q + nQ;
    unsigned short* Vt = K + nQ;
    unsigned short* xb = Vt;                      // alias: dead before Vt written
    unsigned short* Wt = Vt + nQ;
    float* lpart = (float*)(Wt + (size_t)3 * D_ * D_);
    float* il    = lpart + (size_t)B_ * PAIRS_ * 128;
    float* O = (float*)d_out;

    hipLaunchKernelGGL(prep_x, dim3(8192), dim3(256), 0, stream, x, xb);
    hipLaunchKernelGGL(prep_w, dim3(16, 16, 3), dim3(256), 0, stream, Wq, Wk, Wv, Wt);
    hipLaunchKernelGGL(qkv_gemm, dim3(8, 128, 3), dim3(256), 0, stream, xb, Wt, Q, K, V);
    hipLaunchKernelGGL(vt_trans, dim3(64, 16, B_), dim3(256), 0, stream, V, Vt);
    hipLaunchKernelGGL(qk_pexp, dim3(PAIRS_, B_), dim3(256), 0, stream, Q, K, P, lpart);
    hipLaunchKernelGGL(merge_il, dim3(NT_, B_), dim3(128), 0, stream, lpart, il);
    hipLaunchKernelGGL(pv_gemm, dim3(512), dim3(256), 0, stream, P, Vt, il, O);
}